// Round 2
// baseline (32624.371 us; speedup 1.0000x reference)
//
#include <hip/hip_runtime.h>
#include <math.h>

#define NB 256   // batch
#define NN 256   // N (code length)
#define NK 128   // K (info bits)
#define ND 256   // D (embedding dim)
#define NH 512   // H (hidden dim)
#define NT 1024  // threads per block

// output layout (floats) in d_out, reference return order:
#define OUT_X 0
#define OUT_F 65536
#define OUT_U 131072
#define OUT_P 196608

#define EPB (255 * ND)  // E floats per batch (levels 1..8)
#define LPB 255         // partial-sum bits per batch

__device__ __forceinline__ int loff(int d) { return 256 - (1 << (9 - d)); }

// One MLP stage: P rows, input [E[2p], E[2p+1], (bn) label_emb[h1[p]]].
// 1024 threads = 4 groups (g=tid>>8) x 256 col-threads (cq=tid&255).
// PC>=4: groups own rows.  PC==2: k-split 2.  PC==1: k-split 4.
template <int PC, int KIN>
__device__ __forceinline__ void mlp_stage(
    int P,
    const float* __restrict__ Esrc,   // nullptr => root (obs_emb[2] broadcast)
    float* __restrict__ Edst,
    const int* __restrict__ h1bits,
    const float* __restrict__ obs2, const float* __restrict__ lemb,
    const float* __restrict__ W1, const float* __restrict__ b1,
    const float* __restrict__ W2, const float* __restrict__ b2,
    float* inS, float* hidS, float* partS, int tid)
{
  const int g = tid >> 8;
  const int cq = tid & 255;
  const int c2 = cq * 2;
  for (int p0 = 0; p0 < P; p0 += PC) {
    // ---- stage input rows into LDS ----
    for (int i = tid; i < PC * KIN; i += NT) {
      const int p = i / KIN, k = i - p * KIN;
      const int pos = p0 + p;
      float v;
      if (KIN == 768 && k >= 512) {
        v = lemb[h1bits[pos] * ND + (k - 512)];
      } else {
        const int col = k & 255;
        v = Esrc ? Esrc[(2 * pos + ((k >> 8) & 1)) * ND + col] : obs2[col];
      }
      inS[i] = v;
    }
    __syncthreads();

    // ---- GEMM1: hidden = relu(in @ W1 + b1) ----
    if (PC >= 4) {
      constexpr int RP = (PC >= 4) ? (PC / 4) : 1;
      float a0[RP], a1[RP];
#pragma unroll
      for (int r = 0; r < RP; ++r) { a0[r] = 0.f; a1[r] = 0.f; }
#pragma unroll 4
      for (int k = 0; k < KIN; ++k) {
        const float2 w = *(const float2*)&W1[(size_t)k * NH + c2];
#pragma unroll
        for (int r = 0; r < RP; ++r) {
          const float iv = inS[(g * RP + r) * KIN + k];
          a0[r] += iv * w.x; a1[r] += iv * w.y;
        }
      }
      const float bb0 = b1[c2], bb1 = b1[c2 + 1];
#pragma unroll
      for (int r = 0; r < RP; ++r) {
        float h0 = fmaxf(a0[r] + bb0, 0.f);
        float h1 = fmaxf(a1[r] + bb1, 0.f);
        *(float2*)&hidS[(g * RP + r) * NH + c2] = make_float2(h0, h1);
      }
      __syncthreads();
    } else if (PC == 2) {
      const int row = g & 1, kh = g >> 1;
      float a0 = 0.f, a1 = 0.f;
#pragma unroll 4
      for (int k = kh * (KIN / 2); k < (kh + 1) * (KIN / 2); ++k) {
        const float2 w = *(const float2*)&W1[(size_t)k * NH + c2];
        const float iv = inS[row * KIN + k];
        a0 += iv * w.x; a1 += iv * w.y;
      }
      *(float2*)&partS[(kh * 2 + row) * NH + c2] = make_float2(a0, a1);
      __syncthreads();
      {
        const int row2 = tid >> 9, col = tid & 511;
        const float h = partS[row2 * NH + col] + partS[(2 + row2) * NH + col] + b1[col];
        hidS[row2 * NH + col] = fmaxf(h, 0.f);
      }
      __syncthreads();
    } else {  // PC == 1
      float a0 = 0.f, a1 = 0.f;
#pragma unroll 4
      for (int k = g * (KIN / 4); k < (g + 1) * (KIN / 4); ++k) {
        const float2 w = *(const float2*)&W1[(size_t)k * NH + c2];
        const float iv = inS[k];
        a0 += iv * w.x; a1 += iv * w.y;
      }
      *(float2*)&partS[g * NH + c2] = make_float2(a0, a1);
      __syncthreads();
      if (tid < NH) {
        const float h = partS[tid] + partS[NH + tid] + partS[2 * NH + tid] + partS[3 * NH + tid] + b1[tid];
        hidS[tid] = fmaxf(h, 0.f);
      }
      __syncthreads();
    }

    // ---- GEMM2: out = hidden @ W2 + b2 ----
    if (PC >= 4) {
      constexpr int RP = (PC >= 4) ? (PC / 4) : 1;
      float acc[RP];
#pragma unroll
      for (int r = 0; r < RP; ++r) acc[r] = 0.f;
#pragma unroll 4
      for (int h = 0; h < NH; ++h) {
        const float w = W2[(size_t)h * ND + cq];
#pragma unroll
        for (int r = 0; r < RP; ++r) acc[r] += hidS[(g * RP + r) * NH + h] * w;
      }
      const float bo = b2[cq];
#pragma unroll
      for (int r = 0; r < RP; ++r) Edst[(size_t)(p0 + g * RP + r) * ND + cq] = acc[r] + bo;
    } else if (PC == 2) {
      const int row = g & 1, hh = g >> 1;
      float acc = 0.f;
#pragma unroll 4
      for (int h = hh * (NH / 2); h < (hh + 1) * (NH / 2); ++h)
        acc += hidS[row * NH + h] * W2[(size_t)h * ND + cq];
      partS[(hh * 2 + row) * ND + cq] = acc;
      __syncthreads();
      if (tid < 512) {
        const int row2 = tid >> 8, col = tid & 255;
        Edst[(size_t)(p0 + row2) * ND + col] =
            partS[row2 * ND + col] + partS[(2 + row2) * ND + col] + b2[col];
      }
    } else {  // PC == 1
      float acc = 0.f;
#pragma unroll 4
      for (int h = g * (NH / 4); h < (g + 1) * (NH / 4); ++h)
        acc += hidS[h] * W2[(size_t)h * ND + cq];
      partS[g * ND + cq] = acc;
      __syncthreads();
      if (tid < 256)
        Edst[(size_t)p0 * ND + tid] =
            partS[tid] + partS[ND + tid] + partS[2 * ND + tid] + partS[3 * ND + tid] + b2[tid];
    }
    __syncthreads();
  }
}

__global__ __launch_bounds__(NT, 1) void sc_monolith(
    const int* __restrict__ info_bits, const float* __restrict__ rv,
    const int* __restrict__ info_set,
    const float* __restrict__ obs_emb, const float* __restrict__ label_emb,
    const float* __restrict__ cnW1, const float* __restrict__ cnb1,
    const float* __restrict__ cnW2, const float* __restrict__ cnb2,
    const float* __restrict__ bnW1, const float* __restrict__ bnb1,
    const float* __restrict__ bnW2, const float* __restrict__ bnb2,
    const float* __restrict__ llrW, const float* __restrict__ llrb,
    float* __restrict__ out, float* __restrict__ Ebuf, int* __restrict__ Lbuf)
{
  __shared__ float inS[8 * 768];   // 24 KB
  __shared__ float hidS[8 * 512];  // 16 KB
  __shared__ float partS[2048];    // 8 KB (k-split partials)
  __shared__ float red[512];
  __shared__ int curS0[256], nxtS0[256];

  const int tid = threadIdx.x;
  const int b = blockIdx.x;
  float* E = Ebuf + (size_t)b * EPB;
  int* L = Lbuf + (size_t)b * LPB;
  const float* obs2 = obs_emb + 2 * ND;

  auto cn = [&](int d) {
    const float* src = (d == 0) ? nullptr : (E + loff(d) * ND);
    float* dst = E + loff(d + 1) * ND;
    const int P = 1 << (7 - d);
    switch (d) {
      case 0: case 1: case 2: case 3: case 4:
        mlp_stage<8, 512>(P, src, dst, nullptr, obs2, label_emb, cnW1, cnb1, cnW2, cnb2, inS, hidS, partS, tid); break;
      case 5:
        mlp_stage<4, 512>(P, src, dst, nullptr, obs2, label_emb, cnW1, cnb1, cnW2, cnb2, inS, hidS, partS, tid); break;
      case 6:
        mlp_stage<2, 512>(P, src, dst, nullptr, obs2, label_emb, cnW1, cnb1, cnW2, cnb2, inS, hidS, partS, tid); break;
      default:
        mlp_stage<1, 512>(P, src, dst, nullptr, obs2, label_emb, cnW1, cnb1, cnW2, cnb2, inS, hidS, partS, tid); break;
    }
  };
  auto bn = [&](int d) {
    const float* src = (d == 0) ? nullptr : (E + loff(d) * ND);
    float* dst = E + loff(d + 1) * ND;
    const int* h1 = L + loff(d + 1);
    const int P = 1 << (7 - d);
    switch (d) {
      case 0: case 1: case 2: case 3: case 4:
        mlp_stage<8, 768>(P, src, dst, h1, obs2, label_emb, bnW1, bnb1, bnW2, bnb2, inS, hidS, partS, tid); break;
      case 5:
        mlp_stage<4, 768>(P, src, dst, h1, obs2, label_emb, bnW1, bnb1, bnW2, bnb2, inS, hidS, partS, tid); break;
      case 6:
        mlp_stage<2, 768>(P, src, dst, h1, obs2, label_emb, bnW1, bnb1, bnW2, bnb2, inS, hidS, partS, tid); break;
      default:
        mlp_stage<1, 768>(P, src, dst, h1, obs2, label_emb, bnW1, bnb1, bnW2, bnb2, inS, hidS, partS, tid); break;
    }
  };

  auto leaf = [&](int off) {
    const float* E8 = E + loff(8) * ND;
    if (tid < 256) {
      const float ev = E8[tid];
      red[tid] = ev * llrW[2 * tid];
      red[256 + tid] = ev * llrW[2 * tid + 1];
    }
    __syncthreads();
    for (int s = 128; s > 0; s >>= 1) {
      if (tid < s) { red[tid] += red[tid + s]; red[256 + tid] += red[256 + tid + s]; }
      __syncthreads();
    }
    const float l0 = red[0] + llrb[0];
    const float l1 = red[256] + llrb[1];
    const float m = fmaxf(l0, l1);
    const float e0 = expf(l0 - m), e1 = expf(l1 - m);
    const float s = e0 + e1;
    const float p0 = e0 / s, p1 = e1 / s;
    const int hard = (rv[b * NN + off] > p0) ? 1 : 0;
    int lo = 0, hi = NK;
    while (lo < hi) { const int mid = (lo + hi) >> 1; if (info_set[mid] < off) lo = mid + 1; else hi = mid; }
    const int fidx = (lo < NK && info_set[lo] == off) ? lo : -1;
    const int fval = (fidx >= 0) ? info_bits[b * NK + fidx] : 2;
    const int xb = (fval == 2) ? hard : fval;
    if (tid == 0) {
      out[OUT_F + b * NN + off] = (fidx >= 0) ? 2.0f : (float)xb;
      out[OUT_U + b * NN + off] = (float)xb;
      out[OUT_P + (b * NN + off) * 2 + 0] = p0;
      out[OUT_P + (b * NN + off) * 2 + 1] = p1;
      curS0[0] = xb;
    }
    __syncthreads();
    int* cur = curS0; int* nxt = nxtS0;
    int len = 1, lev = 8, idx = off;
    while (idx & 1) {
      const int* Ll = L + loff(lev);
      if (tid < len) {
        const int c = cur[tid];
        nxt[2 * tid] = Ll[tid] ^ c;
        nxt[2 * tid + 1] = c;
      }
      __syncthreads();
      int* t = cur; cur = nxt; nxt = t;
      len <<= 1; idx >>= 1; --lev;
    }
    if (lev > 0) {
      int* Ll = L + loff(lev);
      if (tid < len) Ll[tid] = cur[tid];
    } else {
      if (tid < 256) out[OUT_X + b * NN + tid] = (float)cur[tid];
    }
    __syncthreads();
  };

  for (int d = 0; d <= 7; ++d) cn(d);
  for (int off = 0; off < NN; ++off) {
    leaf(off);
    if (off < NN - 1) {
      const int z = __ffs(off + 1) - 1;
      const int dbn = 7 - z;
      bn(dbn);
      for (int d = dbn + 1; d <= 7; ++d) cn(d);
    }
  }
}

extern "C" void kernel_launch(void* const* d_in, const int* in_sizes, int n_in,
                              void* d_out, int out_size, void* d_ws, size_t ws_size,
                              hipStream_t stream) {
  const int*   info_bits = (const int*)d_in[0];
  const float* rv        = (const float*)d_in[1];
  const int*   info_set  = (const int*)d_in[2];
  const float* obs_emb   = (const float*)d_in[3];
  const float* label_emb = (const float*)d_in[4];
  const float* cnW1      = (const float*)d_in[5];
  const float* cnb1      = (const float*)d_in[6];
  const float* cnW2      = (const float*)d_in[7];
  const float* cnb2      = (const float*)d_in[8];
  const float* bnW1      = (const float*)d_in[9];
  const float* bnb1      = (const float*)d_in[10];
  const float* bnW2      = (const float*)d_in[11];
  const float* bnb2      = (const float*)d_in[12];
  const float* llrW      = (const float*)d_in[13];
  const float* llrb      = (const float*)d_in[14];

  float* out  = (float*)d_out;
  float* Ebuf = (float*)d_ws;
  int*   Lbuf = (int*)((char*)d_ws + (size_t)NB * EPB * sizeof(float));

  sc_monolith<<<dim3(NB), dim3(NT), 0, stream>>>(
      info_bits, rv, info_set, obs_emb, label_emb,
      cnW1, cnb1, cnW2, cnb2, bnW1, bnb1, bnW2, bnb2,
      llrW, llrb, out, Ebuf, Lbuf);
}

// Round 3
// 14820.277 us; speedup vs baseline: 2.2013x; 2.2013x over previous
//
#include <hip/hip_runtime.h>
#include <math.h>

#define NB 256   // batch
#define NN 256   // N (code length)
#define NK 128   // K (info bits)
#define ND 256   // D (embedding dim)
#define NH 512   // H (hidden dim)
#define NT 1024  // threads per block

// output layout (floats) in d_out, reference return order:
#define OUT_X 0
#define OUT_F 65536
#define OUT_U 131072
#define OUT_P 196608

#define EPB (255 * ND)  // E floats per batch (levels 1..8)
#define LPB 255         // partial-sum bits per batch

__device__ __forceinline__ int loff(int d) { return 256 - (1 << (9 - d)); }

// One MLP stage, zero weight-read redundancy:
// GEMM1: 4 k-quarters (q=tid>>8) x 256 col-pair threads; each quarter reads a
//        DISJOINT 128-row slice of W1 (float2 loads), partials reduced in LDS.
// GEMM2: 8 k-eighths (q=tid>>7) x 128 col-pair threads; disjoint 64-row slices
//        of W2, LDS partial reduce.
// BN: u_emb contribution precomputed in cEmbS[bit][col] (added at G1 reduce).
template <int PC, bool BN>
__device__ __forceinline__ void mlp_stage(
    int P,
    const float* __restrict__ Esrc,   // nullptr => root (obs_emb[2] broadcast)
    float* __restrict__ Edst,
    const int* __restrict__ h1bits,
    const float* __restrict__ obs2,
    const float* __restrict__ W1, const float* __restrict__ b1,
    const float* __restrict__ W2, const float* __restrict__ b2,
    const float* cEmbS, float* inS, float* hidS, float* partS, int* bitS,
    int tid)
{
  for (int p0 = 0; p0 < P; p0 += PC) {
    // ---- stage input rows (and bn bits) into LDS ----
    for (int i = tid; i < PC * 512; i += NT) {
      const int p = i >> 9, k = i & 511;
      const int pos = p0 + p;
      inS[i] = Esrc ? Esrc[(size_t)(2 * pos + (k >> 8)) * ND + (k & 255)]
                    : obs2[k & 255];
    }
    if (BN && tid < PC) bitS[tid] = h1bits[p0 + tid];
    __syncthreads();

    // ---- GEMM1 partials: quarter q handles k in [q*128, q*128+128) ----
    {
      const int q = tid >> 8;
      const int c2 = (tid & 255) << 1;
      float a0[PC], a1[PC];
#pragma unroll
      for (int r = 0; r < PC; ++r) { a0[r] = 0.f; a1[r] = 0.f; }
      const float* w1p = W1 + (size_t)(q * 128) * NH + c2;
#pragma unroll 2
      for (int kk = 0; kk < 128; ++kk) {
        const float2 w = *(const float2*)(w1p + (size_t)kk * NH);
        const int k = q * 128 + kk;
#pragma unroll
        for (int r = 0; r < PC; ++r) {
          const float iv = inS[r * 512 + k];
          a0[r] += iv * w.x; a1[r] += iv * w.y;
        }
      }
#pragma unroll
      for (int r = 0; r < PC; ++r)
        *(float2*)&partS[(q * PC + r) * 512 + c2] = make_float2(a0[r], a1[r]);
    }
    __syncthreads();

    // ---- GEMM1 reduce -> relu -> hidS ----
    for (int idx = tid; idx < PC * 512; idx += NT) {
      const int row = idx >> 9, col = idx & 511;
      float s = partS[(0 * PC + row) * 512 + col]
              + partS[(1 * PC + row) * 512 + col]
              + partS[(2 * PC + row) * 512 + col]
              + partS[(3 * PC + row) * 512 + col] + b1[col];
      if (BN) s += cEmbS[bitS[row] * 512 + col];
      hidS[row * 512 + col] = fmaxf(s, 0.f);
    }
    __syncthreads();

    // ---- GEMM2 partials: eighth q handles h in [q*64, q*64+64) ----
    {
      const int q = tid >> 7;
      const int c2 = (tid & 127) << 1;
      float b0[PC], b1v[PC];
#pragma unroll
      for (int r = 0; r < PC; ++r) { b0[r] = 0.f; b1v[r] = 0.f; }
      const float* w2p = W2 + (size_t)(q * 64) * ND + c2;
#pragma unroll 2
      for (int hh = 0; hh < 64; ++hh) {
        const float2 w = *(const float2*)(w2p + (size_t)hh * ND);
        const int h = q * 64 + hh;
#pragma unroll
        for (int r = 0; r < PC; ++r) {
          const float hv = hidS[r * 512 + h];
          b0[r] += hv * w.x; b1v[r] += hv * w.y;
        }
      }
#pragma unroll
      for (int r = 0; r < PC; ++r)
        *(float2*)&partS[(q * PC + r) * 256 + c2] = make_float2(b0[r], b1v[r]);
    }
    __syncthreads();

    // ---- GEMM2 reduce -> Edst ----
    for (int idx = tid; idx < PC * 256; idx += NT) {
      const int row = idx >> 8, col = idx & 255;
      float s = b2[col];
#pragma unroll
      for (int q = 0; q < 8; ++q) s += partS[(q * PC + row) * 256 + col];
      Edst[(size_t)(p0 + row) * ND + col] = s;
    }
    __syncthreads();
  }
}

__global__ __launch_bounds__(NT, 1) void sc_monolith(
    const int* __restrict__ info_bits, const float* __restrict__ rv,
    const int* __restrict__ info_set,
    const float* __restrict__ obs_emb, const float* __restrict__ label_emb,
    const float* __restrict__ cnW1, const float* __restrict__ cnb1,
    const float* __restrict__ cnW2, const float* __restrict__ cnb2,
    const float* __restrict__ bnW1, const float* __restrict__ bnb1,
    const float* __restrict__ bnW2, const float* __restrict__ bnb2,
    const float* __restrict__ llrW, const float* __restrict__ llrb,
    float* __restrict__ out, float* __restrict__ Ebuf, int* __restrict__ Lbuf)
{
  __shared__ float inS[8 * 512];    // 16 KB
  __shared__ float hidS[8 * 512];   // 16 KB
  __shared__ float partS[16384];    // 64 KB (k-split partials)
  __shared__ float cEmbS[2 * 512];  // 4 KB  (label_emb @ bnW1[512:768])
  __shared__ float redS[8];
  __shared__ int bitS[8];
  __shared__ int curS0[256], nxtS0[256];

  const int tid = threadIdx.x;
  const int b = blockIdx.x;
  float* E = Ebuf + (size_t)b * EPB;
  int* L = Lbuf + (size_t)b * LPB;
  const float* obs2 = obs_emb + 2 * ND;

  // ---- precompute bn u_emb contributions: cEmbS[bit][col] ----
  {
    const int bit = tid >> 9, col = tid & 511;
    float s = 0.f;
#pragma unroll 4
    for (int j = 0; j < 256; ++j)
      s += label_emb[bit * ND + j] * bnW1[(size_t)(512 + j) * NH + col];
    cEmbS[bit * 512 + col] = s;
  }
  __syncthreads();

  auto cn = [&](int d) {
    const float* src = (d == 0) ? nullptr : (E + loff(d) * ND);
    float* dst = E + loff(d + 1) * ND;
    const int P = 1 << (7 - d);
    switch (d) {
      case 0: case 1: case 2: case 3: case 4:
        mlp_stage<8, false>(P, src, dst, nullptr, obs2, cnW1, cnb1, cnW2, cnb2, cEmbS, inS, hidS, partS, bitS, tid); break;
      case 5:
        mlp_stage<4, false>(P, src, dst, nullptr, obs2, cnW1, cnb1, cnW2, cnb2, cEmbS, inS, hidS, partS, bitS, tid); break;
      case 6:
        mlp_stage<2, false>(P, src, dst, nullptr, obs2, cnW1, cnb1, cnW2, cnb2, cEmbS, inS, hidS, partS, bitS, tid); break;
      default:
        mlp_stage<1, false>(P, src, dst, nullptr, obs2, cnW1, cnb1, cnW2, cnb2, cEmbS, inS, hidS, partS, bitS, tid); break;
    }
  };
  auto bn = [&](int d) {
    const float* src = (d == 0) ? nullptr : (E + loff(d) * ND);
    float* dst = E + loff(d + 1) * ND;
    const int* h1 = L + loff(d + 1);
    const int P = 1 << (7 - d);
    switch (d) {
      case 0: case 1: case 2: case 3: case 4:
        mlp_stage<8, true>(P, src, dst, h1, obs2, bnW1, bnb1, bnW2, bnb2, cEmbS, inS, hidS, partS, bitS, tid); break;
      case 5:
        mlp_stage<4, true>(P, src, dst, h1, obs2, bnW1, bnb1, bnW2, bnb2, cEmbS, inS, hidS, partS, bitS, tid); break;
      case 6:
        mlp_stage<2, true>(P, src, dst, h1, obs2, bnW1, bnb1, bnW2, bnb2, cEmbS, inS, hidS, partS, bitS, tid); break;
      default:
        mlp_stage<1, true>(P, src, dst, h1, obs2, bnW1, bnb1, bnW2, bnb2, cEmbS, inS, hidS, partS, bitS, tid); break;
    }
  };

  auto leaf = [&](int off) {
    const float* E8 = E + loff(8) * ND;
    if (tid < 256) {
      const float ev = E8[tid];
      float v0 = ev * llrW[2 * tid];
      float v1 = ev * llrW[2 * tid + 1];
#pragma unroll
      for (int o = 32; o > 0; o >>= 1) {
        v0 += __shfl_down(v0, o);
        v1 += __shfl_down(v1, o);
      }
      if ((tid & 63) == 0) {
        const int w = tid >> 6;
        redS[w] = v0; redS[4 + w] = v1;
      }
    }
    __syncthreads();
    if (tid == 0) {
      const float l0 = redS[0] + redS[1] + redS[2] + redS[3] + llrb[0];
      const float l1 = redS[4] + redS[5] + redS[6] + redS[7] + llrb[1];
      const float m = fmaxf(l0, l1);
      const float e0 = expf(l0 - m), e1 = expf(l1 - m);
      const float s = e0 + e1;
      const float p0 = e0 / s, p1 = e1 / s;
      const int hard = (rv[b * NN + off] > p0) ? 1 : 0;
      int lo = 0, hi = NK;
      while (lo < hi) { const int mid = (lo + hi) >> 1; if (info_set[mid] < off) lo = mid + 1; else hi = mid; }
      const int fidx = (lo < NK && info_set[lo] == off) ? lo : -1;
      const int fval = (fidx >= 0) ? info_bits[b * NK + fidx] : 2;
      const int xb = (fval == 2) ? hard : fval;
      out[OUT_F + b * NN + off] = (fidx >= 0) ? 2.0f : (float)xb;
      out[OUT_U + b * NN + off] = (float)xb;
      out[OUT_P + (b * NN + off) * 2 + 0] = p0;
      out[OUT_P + (b * NN + off) * 2 + 1] = p1;
      curS0[0] = xb;
    }
    __syncthreads();
    int* cur = curS0; int* nxt = nxtS0;
    int len = 1, lev = 8, idx = off;
    while (idx & 1) {
      const int* Ll = L + loff(lev);
      if (tid < len) {
        const int c = cur[tid];
        nxt[2 * tid] = Ll[tid] ^ c;
        nxt[2 * tid + 1] = c;
      }
      __syncthreads();
      int* t = cur; cur = nxt; nxt = t;
      len <<= 1; idx >>= 1; --lev;
    }
    if (lev > 0) {
      int* Ll = L + loff(lev);
      if (tid < len) Ll[tid] = cur[tid];
    } else {
      if (tid < 256) out[OUT_X + b * NN + tid] = (float)cur[tid];
    }
    __syncthreads();
  };

  for (int d = 0; d <= 7; ++d) cn(d);
  for (int off = 0; off < NN; ++off) {
    leaf(off);
    if (off < NN - 1) {
      const int z = __ffs(off + 1) - 1;
      const int dbn = 7 - z;
      bn(dbn);
      for (int d = dbn + 1; d <= 7; ++d) cn(d);
    }
  }
}

extern "C" void kernel_launch(void* const* d_in, const int* in_sizes, int n_in,
                              void* d_out, int out_size, void* d_ws, size_t ws_size,
                              hipStream_t stream) {
  const int*   info_bits = (const int*)d_in[0];
  const float* rv        = (const float*)d_in[1];
  const int*   info_set  = (const int*)d_in[2];
  const float* obs_emb   = (const float*)d_in[3];
  const float* label_emb = (const float*)d_in[4];
  const float* cnW1      = (const float*)d_in[5];
  const float* cnb1      = (const float*)d_in[6];
  const float* cnW2      = (const float*)d_in[7];
  const float* cnb2      = (const float*)d_in[8];
  const float* bnW1      = (const float*)d_in[9];
  const float* bnb1      = (const float*)d_in[10];
  const float* bnW2      = (const float*)d_in[11];
  const float* bnb2      = (const float*)d_in[12];
  const float* llrW      = (const float*)d_in[13];
  const float* llrb      = (const float*)d_in[14];

  float* out  = (float*)d_out;
  float* Ebuf = (float*)d_ws;
  int*   Lbuf = (int*)((char*)d_ws + (size_t)NB * EPB * sizeof(float));

  sc_monolith<<<dim3(NB), dim3(NT), 0, stream>>>(
      info_bits, rv, info_set, obs_emb, label_emb,
      cnW1, cnb1, cnW2, cnb2, bnW1, bnb1, bnW2, bnb2,
      llrW, llrb, out, Ebuf, Lbuf);
}